// Round 1
// baseline (326.550 us; speedup 1.0000x reference)
//
#include <hip/hip_runtime.h>
#include <hip/hip_bf16.h>

#define BB 8
#define NN 2048
#define MM 2048
#define CC 256
#define TILE 64
#define BK 32
#define LDP 68   // padded leading dim (floats) for LDS tiles; 68*4B = 16B-aligned rows

// ---------------- row inverse-norm kernel ----------------
// One wave per row of C=256 floats (64 lanes x float4).
__global__ void norm_kernel(const float* __restrict__ x1, const float* __restrict__ x2,
                            float* __restrict__ inv1, float* __restrict__ inv2) {
    int gwave = (blockIdx.x * blockDim.x + threadIdx.x) >> 6;
    int lane  = threadIdx.x & 63;
    const float* src;
    float* dst;
    int row;
    if (gwave < BB * NN) { src = x1; dst = inv1; row = gwave; }
    else                 { src = x2; dst = inv2; row = gwave - BB * NN; }
    float4 v = reinterpret_cast<const float4*>(src + (size_t)row * CC)[lane];
    float ss = v.x * v.x + v.y * v.y + v.z * v.z + v.w * v.w;
#pragma unroll
    for (int off = 32; off; off >>= 1) ss += __shfl_down(ss, off);
    if (lane == 0) dst[row] = 1.0f / fmaxf(sqrtf(ss), 1e-8f);
}

// ---------------- accumulator zeroing ----------------
__global__ void zero_acc(float* __restrict__ lsum, unsigned int* __restrict__ vcnt,
                         unsigned int* __restrict__ flags) {
    int t = threadIdx.x;
    if (t < BB) {
        lsum[t]     = 0.0f;
        vcnt[t]     = 0u;
        flags[t]    = 0u;   // has positive
        flags[BB+t] = 0u;   // has negative
    }
}

// ---------------- fused cos-sim GEMM + BCE reduce ----------------
__global__ __launch_bounds__(256) void fused_kernel(
    const int*   __restrict__ z,
    const float* __restrict__ x1, const float* __restrict__ x2,
    const float* __restrict__ inv1, const float* __restrict__ inv2,
    const float* __restrict__ tptr, const float* __restrict__ bptr,
    float* __restrict__ lsum, unsigned int* __restrict__ vcnt,
    unsigned int* __restrict__ flags) {

    __shared__ float As[BK][LDP];
    __shared__ float Bs[BK][LDP];

    const int b   = blockIdx.z;
    const int n0  = blockIdx.y * TILE;
    const int m0  = blockIdx.x * TILE;
    const int tid = threadIdx.x;

    const float* A  = x1 + (size_t)b * NN * CC;
    const float* Bm = x2 + (size_t)b * MM * CC;

    const int row = (tid >> 4) << 2;   // 0..60
    const int col = (tid & 15) << 2;   // 0..60

    float acc[4][4];
#pragma unroll
    for (int i = 0; i < 4; i++)
#pragma unroll
        for (int j = 0; j < 4; j++) acc[i][j] = 0.0f;

    for (int k0 = 0; k0 < CC; k0 += BK) {
        __syncthreads();   // previous compute done before overwrite
#pragma unroll
        for (int i = 0; i < 2; i++) {
            int f  = i * 256 + tid;      // 0..511
            int r  = f >> 3;             // 0..63
            int c4 = (f & 7) << 2;       // 0,4,..,28
            float4 va = *reinterpret_cast<const float4*>(A  + (size_t)(n0 + r) * CC + k0 + c4);
            As[c4 + 0][r] = va.x; As[c4 + 1][r] = va.y;
            As[c4 + 2][r] = va.z; As[c4 + 3][r] = va.w;
            float4 vb = *reinterpret_cast<const float4*>(Bm + (size_t)(m0 + r) * CC + k0 + c4);
            Bs[c4 + 0][r] = vb.x; Bs[c4 + 1][r] = vb.y;
            Bs[c4 + 2][r] = vb.z; Bs[c4 + 3][r] = vb.w;
        }
        __syncthreads();
#pragma unroll
        for (int k = 0; k < BK; k++) {
            float4 a4 = *reinterpret_cast<const float4*>(&As[k][row]);
            float4 b4 = *reinterpret_cast<const float4*>(&Bs[k][col]);
            float av[4] = {a4.x, a4.y, a4.z, a4.w};
            float bw[4] = {b4.x, b4.y, b4.z, b4.w};
#pragma unroll
            for (int i = 0; i < 4; i++)
#pragma unroll
                for (int j = 0; j < 4; j++)
                    acc[i][j] = fmaf(av[i], bw[j], acc[i][j]);
        }
    }

    // ---------------- epilogue: scale, z-mask, log-sigmoid ----------------
    const float tv  = *tptr;
    const float bsc = *bptr;
    float sA[4], sB[4];
#pragma unroll
    for (int i = 0; i < 4; i++) sA[i] = inv1[b * NN + n0 + row + i];
#pragma unroll
    for (int j = 0; j < 4; j++) sB[j] = inv2[b * MM + m0 + col + j];

    float local_sum = 0.0f;
    int   local_cnt = 0;
    bool  anyp = false, anyn = false;
#pragma unroll
    for (int i = 0; i < 4; i++) {
        const int* zr = z + ((size_t)b * NN + n0 + row + i) * MM + m0 + col;
        int4 zv = *reinterpret_cast<const int4*>(zr);
        int za[4] = {zv.x, zv.y, zv.z, zv.w};
#pragma unroll
        for (int j = 0; j < 4; j++) {
            int zij = za[j];
            if (zij != 0) {
                float cs = acc[i][j] * sA[i] * sB[j];
                float y  = (float)zij * fmaf(tv, cs, -bsc);
                float ls = fminf(y, 0.0f) - log1pf(__expf(-fabsf(y)));
                local_sum += ls;
                local_cnt += 1;
                if (zij > 0) anyp = true; else anyn = true;
            }
        }
    }

    // ---------------- block reduction ----------------
    const int lane = tid & 63;
    const int wv   = tid >> 6;
#pragma unroll
    for (int off = 32; off; off >>= 1) {
        local_sum += __shfl_down(local_sum, off);
        local_cnt += __shfl_down(local_cnt, off);
    }
    unsigned long long mp = __ballot(anyp);
    unsigned long long mn = __ballot(anyn);

    __shared__ float        s_sum[4];
    __shared__ unsigned int s_cnt[4];
    __shared__ unsigned int s_flag[2];
    __syncthreads();
    if (tid < 2) s_flag[tid] = 0u;
    __syncthreads();
    if (lane == 0) {
        s_sum[wv] = local_sum;
        s_cnt[wv] = (unsigned int)local_cnt;
        if (mp) atomicOr(&s_flag[0], 1u);
        if (mn) atomicOr(&s_flag[1], 1u);
    }
    __syncthreads();
    if (tid == 0) {
        float        ts = s_sum[0] + s_sum[1] + s_sum[2] + s_sum[3];
        unsigned int tc = s_cnt[0] + s_cnt[1] + s_cnt[2] + s_cnt[3];
        atomicAdd(&lsum[b], ts);
        atomicAdd(&vcnt[b], tc);
        if (s_flag[0]) atomicOr(&flags[b], 1u);
        if (s_flag[1]) atomicOr(&flags[BB + b], 1u);
    }
}

// ---------------- finalize: batch filter + division ----------------
__global__ void finalize_kernel(const float* __restrict__ lsum,
                                const unsigned int* __restrict__ vcnt,
                                const unsigned int* __restrict__ flags,
                                float* __restrict__ out) {
    if (threadIdx.x == 0 && blockIdx.x == 0) {
        double s = 0.0, c = 0.0;
        for (int b = 0; b < BB; b++) {
            if (flags[b] && flags[BB + b]) {
                s += (double)lsum[b];
                c += (double)vcnt[b];
            }
        }
        out[0] = (float)(-s / c);
    }
}

extern "C" void kernel_launch(void* const* d_in, const int* in_sizes, int n_in,
                              void* d_out, int out_size, void* d_ws, size_t ws_size,
                              hipStream_t stream) {
    const int*   z   = (const int*)  d_in[0];
    const float* x1  = (const float*)d_in[1];
    const float* x2  = (const float*)d_in[2];
    const float* tp  = (const float*)d_in[3];
    const float* bp  = (const float*)d_in[4];
    float* out = (float*)d_out;

    char* ws = (char*)d_ws;
    float*        inv1  = (float*)ws;                       // B*N floats = 64 KiB
    float*        inv2  = (float*)(ws + 65536);             // B*M floats = 64 KiB
    float*        lsum  = (float*)(ws + 131072);            // 8 floats
    unsigned int* vcnt  = (unsigned int*)(ws + 131072 + 32);
    unsigned int* flags = (unsigned int*)(ws + 131072 + 64); // 16 uints

    hipLaunchKernelGGL(zero_acc, dim3(1), dim3(64), 0, stream, lsum, vcnt, flags);

    // 32768 rows total, 4 rows (waves) per block
    hipLaunchKernelGGL(norm_kernel, dim3((BB * (NN + MM)) / 4 / 64), dim3(256), 0, stream,
                       x1, x2, inv1, inv2);

    hipLaunchKernelGGL(fused_kernel, dim3(MM / TILE, NN / TILE, BB), dim3(256), 0, stream,
                       z, x1, x2, inv1, inv2, tp, bp, lsum, vcnt, flags);

    hipLaunchKernelGGL(finalize_kernel, dim3(1), dim3(64), 0, stream,
                       lsum, vcnt, flags, out);
}

// Round 2
// 124.972 us; speedup vs baseline: 2.6130x; 2.6130x over previous
//
#include <hip/hip_runtime.h>
#include <hip/hip_bf16.h>
#include <stdint.h>

#define BB 8
#define NN 2048
#define MM 2048
#define CC 256

typedef __attribute__((ext_vector_type(8))) short short8;
typedef __attribute__((ext_vector_type(4))) float f32x4;

__device__ __forceinline__ void gl_lds16(const void* g, void* l) {
    __builtin_amdgcn_global_load_lds(
        (const __attribute__((address_space(1))) void*)g,
        (__attribute__((address_space(3))) void*)l, 16, 0, 0);
}

__device__ __forceinline__ unsigned short f2bf(float f) {
    __hip_bfloat16 h = __float2bfloat16(f);
    return *reinterpret_cast<unsigned short*>(&h);
}

// ---------------- normalize + cast + swizzle-store pre-pass ----------------
// One wave per row of C=256 floats. Output layout (bytes):
//   row*512 + c*64 + kbL*16 + j*2   where k = c*32 + kb*8 + j, kbL = kb ^ ((row>>1)&3)
// This is exactly what linear global_load_lds staging + swizzled ds_read expects.
__global__ __launch_bounds__(256) void norm_cast_kernel(
    const float* __restrict__ x1, const float* __restrict__ x2,
    char* __restrict__ out1, char* __restrict__ out2) {
    int gwave = (blockIdx.x * blockDim.x + threadIdx.x) >> 6;
    int lane  = threadIdx.x & 63;
    const float* src; char* dst; int row;
    if (gwave < BB * NN) { src = x1; dst = out1; row = gwave; }
    else                 { src = x2; dst = out2; row = gwave - BB * NN; }
    float4 v = reinterpret_cast<const float4*>(src + (size_t)row * CC)[lane];
    float ss = v.x * v.x + v.y * v.y + v.z * v.z + v.w * v.w;
#pragma unroll
    for (int off = 32; off; off >>= 1) ss += __shfl_xor(ss, off);
    float inv = 1.0f / fmaxf(sqrtf(ss), 1e-8f);
    ushort4 h;
    h.x = f2bf(v.x * inv); h.y = f2bf(v.y * inv);
    h.z = f2bf(v.z * inv); h.w = f2bf(v.w * inv);
    int c   = lane >> 3;                                  // 0..7 (32-k chunk)
    int kb  = (lane >> 1) & 3;                            // logical k-block of 8
    int kbL = kb ^ ((row >> 1) & 3);                      // swizzled position
    char* p = dst + (size_t)row * 512 + c * 64 + kbL * 16 + (lane & 1) * 8;
    *reinterpret_cast<ushort4*>(p) = h;
}

// ---------------- accumulator zeroing ----------------
__global__ void zero_acc(float* __restrict__ lsum, unsigned int* __restrict__ vcnt,
                         unsigned int* __restrict__ flags) {
    int t = threadIdx.x;
    if (t < BB) {
        lsum[t]     = 0.0f;
        vcnt[t]     = 0u;
        flags[t]    = 0u;
        flags[BB+t] = 0u;
    }
}

// ---------------- fused MFMA cos-sim + BCE reduce ----------------
// 128x128 tile, 4 waves (2x2), each wave 64x64 = 4x4 fragments of 16x16x32 bf16.
__global__ __launch_bounds__(256) void fused_mfma_kernel(
    const int*  __restrict__ z,
    const char* __restrict__ nA, const char* __restrict__ nB,
    const float* __restrict__ tptr, const float* __restrict__ bptr,
    float* __restrict__ lsum, unsigned int* __restrict__ vcnt,
    unsigned int* __restrict__ flags) {

    __shared__ __align__(16) char lds[16384];
    char* As = lds;
    char* Bs = lds + 8192;

    const int b    = blockIdx.z;
    const int n0   = blockIdx.y * 128;
    const int m0   = blockIdx.x * 128;
    const int tid  = threadIdx.x;
    const int lane = tid & 63;
    const int wid  = tid >> 6;
    const int wr   = wid >> 1, wc = wid & 1;

    const char* gA = nA + ((size_t)((size_t)b * NN + n0)) * 512;
    const char* gB = nB + ((size_t)((size_t)b * MM + m0)) * 512;

    // staging: wave wid covers LDS chunks q=wid*2, wid*2+1 (1 KiB each = 16 rows)
    const int q = wid * 2;
    const size_t soff = (size_t)(q * 16 + (lane >> 2)) * 512 + (size_t)(lane & 3) * 16;
    const char* srcA0 = gA + soff;
    const char* srcB0 = gB + soff;
    char* dstA = As + q * 1024;   // wave-uniform; HW adds lane*16
    char* dstB = Bs + q * 1024;

    // fragment ds_read offsets (swizzled): row r -> byte r*64 + ((kb ^ ((r>>1)&3))<<4)
    const int l15  = lane & 15;
    const int koff = (((lane >> 4) ^ ((l15 >> 1) & 3)) << 4);
    int aoff[4], boff[4];
#pragma unroll
    for (int m = 0; m < 4; m++) aoff[m] = (wr * 64 + m * 16 + l15) * 64 + koff;
#pragma unroll
    for (int n = 0; n < 4; n++) boff[n] = (wc * 64 + n * 16 + l15) * 64 + koff;

    f32x4 acc[4][4];
#pragma unroll
    for (int m = 0; m < 4; m++)
#pragma unroll
        for (int n = 0; n < 4; n++) acc[m][n] = (f32x4){0.f, 0.f, 0.f, 0.f};

    for (int c = 0; c < CC / 32; c++) {
        __syncthreads();   // LDS free (all waves finished previous compute)
        gl_lds16(srcA0 + c * 64,        dstA);
        gl_lds16(srcA0 + 8192 + c * 64, dstA + 1024);
        gl_lds16(srcB0 + c * 64,        dstB);
        gl_lds16(srcB0 + 8192 + c * 64, dstB + 1024);
        __syncthreads();   // drains vmcnt(0) lgkmcnt(0) for all waves before compute
        short8 af[4], bfr[4];
#pragma unroll
        for (int m = 0; m < 4; m++) af[m]  = *reinterpret_cast<const short8*>(As + aoff[m]);
#pragma unroll
        for (int n = 0; n < 4; n++) bfr[n] = *reinterpret_cast<const short8*>(Bs + boff[n]);
#pragma unroll
        for (int m = 0; m < 4; m++)
#pragma unroll
            for (int n = 0; n < 4; n++)
                acc[m][n] = __builtin_amdgcn_mfma_f32_16x16x32_bf16(af[m], bfr[n], acc[m][n], 0, 0, 0);
    }

    // ---------------- epilogue: z-mask + log-sigmoid + reduce ----------------
    const float tv = *tptr;
    const float bs = *bptr;
    float lsu = 0.0f;
    int   lcnt = 0;
    bool  anyp = false, anyn = false;
#pragma unroll
    for (int m = 0; m < 4; m++) {
#pragma unroll
        for (int r = 0; r < 4; r++) {
            int grow = n0 + wr * 64 + m * 16 + (lane >> 4) * 4 + r;
            const int* zrow = z + ((size_t)b * NN + grow) * MM + m0 + wc * 64 + l15;
#pragma unroll
            for (int n = 0; n < 4; n++) {
                int zij = zrow[n * 16];
                if (zij != 0) {
                    float cs = acc[m][n][r];
                    float y  = (float)zij * fmaf(tv, cs, -bs);
                    float e  = __expf(-fabsf(y));
                    lsu += fminf(y, 0.0f) - __logf(1.0f + e);
                    lcnt++;
                    if (zij > 0) anyp = true; else anyn = true;
                }
            }
        }
    }

    // block reduction
#pragma unroll
    for (int off = 32; off; off >>= 1) {
        lsu  += __shfl_down(lsu, off);
        lcnt += __shfl_down(lcnt, off);
    }
    unsigned long long mp = __ballot(anyp);
    unsigned long long mn = __ballot(anyn);

    __shared__ float        s_sum[4];
    __shared__ unsigned int s_cnt[4];
    __shared__ unsigned int s_flag[2];
    __syncthreads();
    if (tid < 2) s_flag[tid] = 0u;
    __syncthreads();
    if (lane == 0) {
        s_sum[wid] = lsu;
        s_cnt[wid] = (unsigned int)lcnt;
        if (mp) atomicOr(&s_flag[0], 1u);
        if (mn) atomicOr(&s_flag[1], 1u);
    }
    __syncthreads();
    if (tid == 0) {
        float        ts = s_sum[0] + s_sum[1] + s_sum[2] + s_sum[3];
        unsigned int tc = s_cnt[0] + s_cnt[1] + s_cnt[2] + s_cnt[3];
        atomicAdd(&lsum[b], ts);
        atomicAdd(&vcnt[b], tc);
        if (s_flag[0]) atomicOr(&flags[b], 1u);
        if (s_flag[1]) atomicOr(&flags[BB + b], 1u);
    }
}

// ---------------- finalize ----------------
__global__ void finalize_kernel(const float* __restrict__ lsum,
                                const unsigned int* __restrict__ vcnt,
                                const unsigned int* __restrict__ flags,
                                float* __restrict__ out) {
    if (threadIdx.x == 0 && blockIdx.x == 0) {
        double s = 0.0, c = 0.0;
        for (int b = 0; b < BB; b++) {
            if (flags[b] && flags[BB + b]) {
                s += (double)lsum[b];
                c += (double)vcnt[b];
            }
        }
        out[0] = (float)(-s / c);
    }
}

extern "C" void kernel_launch(void* const* d_in, const int* in_sizes, int n_in,
                              void* d_out, int out_size, void* d_ws, size_t ws_size,
                              hipStream_t stream) {
    const int*   z   = (const int*)  d_in[0];
    const float* x1  = (const float*)d_in[1];
    const float* x2  = (const float*)d_in[2];
    const float* tp  = (const float*)d_in[3];
    const float* bp  = (const float*)d_in[4];
    float* out = (float*)d_out;

    char* ws = (char*)d_ws;
    char* normA = ws;                                   // B*N*512 B = 8 MiB
    char* normB = ws + (size_t)BB * NN * 512;           // 8 MiB
    char* accb  = ws + (size_t)BB * (NN + MM) * 512;
    float*        lsum  = (float*)accb;
    unsigned int* vcnt  = (unsigned int*)(accb + 64);
    unsigned int* flags = (unsigned int*)(accb + 128);

    hipLaunchKernelGGL(zero_acc, dim3(1), dim3(64), 0, stream, lsum, vcnt, flags);

    hipLaunchKernelGGL(norm_cast_kernel, dim3(BB * (NN + MM) / 4), dim3(256), 0, stream,
                       x1, x2, normA, normB);

    hipLaunchKernelGGL(fused_mfma_kernel, dim3(MM / 128, NN / 128, BB), dim3(256), 0, stream,
                       z, normA, normB, tp, bp, lsum, vcnt, flags);

    hipLaunchKernelGGL(finalize_kernel, dim3(1), dim3(64), 0, stream,
                       lsum, vcnt, flags, out);
}

// Round 3
// 122.953 us; speedup vs baseline: 2.6559x; 1.0164x over previous
//
#include <hip/hip_runtime.h>
#include <hip/hip_bf16.h>
#include <stdint.h>

#define BB 8
#define NN 2048
#define MM 2048
#define CC 256

typedef __attribute__((ext_vector_type(8))) short short8;
typedef __attribute__((ext_vector_type(4))) float f32x4;

__device__ __forceinline__ void gl_lds16(const void* g, void* l) {
    __builtin_amdgcn_global_load_lds(
        (const __attribute__((address_space(1))) void*)g,
        (__attribute__((address_space(3))) void*)l, 16, 0, 0);
}

__device__ __forceinline__ unsigned short f2bf(float f) {
    __hip_bfloat16 h = __float2bfloat16(f);
    return *reinterpret_cast<unsigned short*>(&h);
}

// ---------------- normalize + cast + swizzle-store pre-pass ----------------
// One wave per row of C=256 floats. Output layout (bytes):
//   row*512 + c*64 + kbL*16 + j*2   where k = c*32 + kb*8 + j, kbL = kb ^ ((row>>1)&3)
__global__ __launch_bounds__(256) void norm_cast_kernel(
    const float* __restrict__ x1, const float* __restrict__ x2,
    char* __restrict__ out1, char* __restrict__ out2) {
    int gwave = (blockIdx.x * blockDim.x + threadIdx.x) >> 6;
    int lane  = threadIdx.x & 63;
    const float* src; char* dst; int row;
    if (gwave < BB * NN) { src = x1; dst = out1; row = gwave; }
    else                 { src = x2; dst = out2; row = gwave - BB * NN; }
    float4 v = reinterpret_cast<const float4*>(src + (size_t)row * CC)[lane];
    float ss = v.x * v.x + v.y * v.y + v.z * v.z + v.w * v.w;
#pragma unroll
    for (int off = 32; off; off >>= 1) ss += __shfl_xor(ss, off);
    float inv = 1.0f / fmaxf(sqrtf(ss), 1e-8f);
    ushort4 h;
    h.x = f2bf(v.x * inv); h.y = f2bf(v.y * inv);
    h.z = f2bf(v.z * inv); h.w = f2bf(v.w * inv);
    int c   = lane >> 3;
    int kb  = (lane >> 1) & 3;
    int kbL = kb ^ ((row >> 1) & 3);
    char* p = dst + (size_t)row * 512 + c * 64 + kbL * 16 + (lane & 1) * 8;
    *reinterpret_cast<ushort4*>(p) = h;
}

// ---------------- z-pack: 2-bit codes in per-(block,thread) order ----------------
// code: 0 -> z=0, 1 -> z=+1, 2 -> z=-1.  slot s = m*16 + r*4 + n -> bits [2s,2s+1]
__global__ __launch_bounds__(256) void zpack_kernel(const int* __restrict__ z,
                                                    uint4* __restrict__ codes) {
    const int b    = blockIdx.z;
    const int n0   = blockIdx.y * 128;
    const int m0   = blockIdx.x * 128;
    const int tid  = threadIdx.x;
    const int lane = tid & 63;
    const int wid  = tid >> 6;
    const int wr   = wid >> 1, wc = wid & 1;
    const int l15  = lane & 15;
    const int q4   = (lane >> 4) << 2;

    uint32_t w[4] = {0u, 0u, 0u, 0u};
#pragma unroll
    for (int m = 0; m < 4; m++) {
#pragma unroll
        for (int r = 0; r < 4; r++) {
            const int grow = n0 + wr * 64 + m * 16 + q4 + r;
            const int* zrow = z + ((size_t)b * NN + grow) * MM + m0 + wc * 64 + l15;
#pragma unroll
            for (int n = 0; n < 4; n++) {
                int zv = zrow[n * 16];
                int s  = m * 16 + r * 4 + n;
                uint32_t code = (zv == 0) ? 0u : ((zv > 0) ? 1u : 2u);
                w[s >> 4] |= code << ((s & 15) * 2);
            }
        }
    }
    size_t blk = ((size_t)b * 16 + blockIdx.y) * 16 + blockIdx.x;
    codes[blk * 256 + tid] = make_uint4(w[0], w[1], w[2], w[3]);
}

// ---------------- accumulator zeroing ----------------
__global__ void zero_acc(float* __restrict__ lsum, unsigned int* __restrict__ vcnt,
                         unsigned int* __restrict__ flags) {
    int t = threadIdx.x;
    if (t < BB) {
        lsum[t]     = 0.0f;
        vcnt[t]     = 0u;
        flags[t]    = 0u;
        flags[BB+t] = 0u;
    }
}

// ---------------- fused MFMA cos-sim + BCE reduce (double-buffered) ----------------
__global__ __launch_bounds__(256) void fused_mfma_kernel(
    const uint4* __restrict__ codes,
    const char* __restrict__ nA, const char* __restrict__ nB,
    const float* __restrict__ tptr, const float* __restrict__ bptr,
    float* __restrict__ lsum, unsigned int* __restrict__ vcnt,
    unsigned int* __restrict__ flags) {

    // [A0 8K][A1 8K][B0 8K][B1 8K]
    __shared__ __align__(16) char lds[32768];

    const int b    = blockIdx.z;
    const int n0   = blockIdx.y * 128;
    const int m0   = blockIdx.x * 128;
    const int tid  = threadIdx.x;
    const int lane = tid & 63;
    const int wid  = tid >> 6;
    const int wr   = wid >> 1, wc = wid & 1;
    const int l15  = lane & 15;

    const char* gA = nA + ((size_t)b * NN + n0) * 512;
    const char* gB = nB + ((size_t)b * MM + m0) * 512;

    const int q = wid * 2;
    const size_t soff = (size_t)(q * 16 + (lane >> 2)) * 512 + (size_t)(lane & 3) * 16;
    const char* srcA0 = gA + soff;
    const char* srcB0 = gB + soff;

#define STAGE(c, i)                                                               \
    do {                                                                          \
        gl_lds16(srcA0 + (c) * 64,        lds + (i) * 8192 + q * 1024);           \
        gl_lds16(srcA0 + 8192 + (c) * 64, lds + (i) * 8192 + q * 1024 + 1024);    \
        gl_lds16(srcB0 + (c) * 64,        lds + 16384 + (i) * 8192 + q * 1024);   \
        gl_lds16(srcB0 + 8192 + (c) * 64, lds + 16384 + (i) * 8192 + q * 1024 + 1024); \
    } while (0)

    const int koff = (((lane >> 4) ^ ((l15 >> 1) & 3)) << 4);
    int aoff[4], boff[4];
#pragma unroll
    for (int m = 0; m < 4; m++) aoff[m] = (wr * 64 + m * 16 + l15) * 64 + koff;
#pragma unroll
    for (int n = 0; n < 4; n++) boff[n] = (wc * 64 + n * 16 + l15) * 64 + koff;

    f32x4 acc[4][4];
#pragma unroll
    for (int m = 0; m < 4; m++)
#pragma unroll
        for (int n = 0; n < 4; n++) acc[m][n] = (f32x4){0.f, 0.f, 0.f, 0.f};

    const size_t blk = ((size_t)b * 16 + blockIdx.y) * 16 + blockIdx.x;

    STAGE(0, 0);
    STAGE(1, 1);
    uint4 zc = codes[blk * 256 + tid];   // in flight across the K-loop

#pragma unroll
    for (int t = 0; t < 8; t++) {
        const int cur = t & 1;
        if (t >= 1 && t < 7) {
            if ((t + 1) & 1) STAGE(t + 1, 1); else STAGE(t + 1, 0);
        }
        if (t < 7) asm volatile("s_waitcnt vmcnt(4)" ::: "memory");
        else       asm volatile("s_waitcnt vmcnt(0)" ::: "memory");
        __builtin_amdgcn_s_barrier();
        asm volatile("" ::: "memory");

        short8 af[4], bfr[4];
#pragma unroll
        for (int m = 0; m < 4; m++)
            af[m] = *reinterpret_cast<const short8*>(lds + cur * 8192 + aoff[m]);
#pragma unroll
        for (int n = 0; n < 4; n++)
            bfr[n] = *reinterpret_cast<const short8*>(lds + 16384 + cur * 8192 + boff[n]);
#pragma unroll
        for (int m = 0; m < 4; m++)
#pragma unroll
            for (int n = 0; n < 4; n++)
                acc[m][n] = __builtin_amdgcn_mfma_f32_16x16x32_bf16(af[m], bfr[n], acc[m][n], 0, 0, 0);

        asm volatile("" ::: "memory");
        __builtin_amdgcn_s_barrier();
    }
#undef STAGE

    // ---------------- epilogue: decode codes + log-sigmoid + reduce ----------------
    const float tv = *tptr;
    const float bs = *bptr;
    uint32_t zw[4] = {zc.x, zc.y, zc.z, zc.w};

    float lsu = 0.0f;
    int   lcnt = 0;
    bool  anyp = false, anyn = false;
#pragma unroll
    for (int m = 0; m < 4; m++) {
#pragma unroll
        for (int r = 0; r < 4; r++) {
#pragma unroll
            for (int n = 0; n < 4; n++) {
                int s = m * 16 + r * 4 + n;
                uint32_t code = (zw[s >> 4] >> ((s & 15) * 2)) & 3u;
                if (code) {
                    float cs  = acc[m][n][r];
                    float sgn = (code == 2u) ? -1.0f : 1.0f;
                    float y   = sgn * fmaf(tv, cs, -bs);
                    float e   = __expf(-fabsf(y));
                    lsu += fminf(y, 0.0f) - __logf(1.0f + e);
                    lcnt++;
                    anyp |= (code == 1u);
                    anyn |= (code == 2u);
                }
            }
        }
    }

#pragma unroll
    for (int off = 32; off; off >>= 1) {
        lsu  += __shfl_down(lsu, off);
        lcnt += __shfl_down(lcnt, off);
    }
    unsigned long long mp = __ballot(anyp);
    unsigned long long mn = __ballot(anyn);

    __shared__ float        s_sum[4];
    __shared__ unsigned int s_cnt[4];
    __shared__ unsigned int s_flag[2];
    __syncthreads();
    if (tid < 2) s_flag[tid] = 0u;
    __syncthreads();
    if (lane == 0) {
        s_sum[wid] = lsu;
        s_cnt[wid] = (unsigned int)lcnt;
        if (mp) atomicOr(&s_flag[0], 1u);
        if (mn) atomicOr(&s_flag[1], 1u);
    }
    __syncthreads();
    if (tid == 0) {
        float        ts = s_sum[0] + s_sum[1] + s_sum[2] + s_sum[3];
        unsigned int tc = s_cnt[0] + s_cnt[1] + s_cnt[2] + s_cnt[3];
        atomicAdd(&lsum[b], ts);
        atomicAdd(&vcnt[b], tc);
        if (s_flag[0]) atomicOr(&flags[b], 1u);
        if (s_flag[1]) atomicOr(&flags[BB + b], 1u);
    }
}

// ---------------- finalize ----------------
__global__ void finalize_kernel(const float* __restrict__ lsum,
                                const unsigned int* __restrict__ vcnt,
                                const unsigned int* __restrict__ flags,
                                float* __restrict__ out) {
    if (threadIdx.x == 0 && blockIdx.x == 0) {
        double s = 0.0, c = 0.0;
        for (int b = 0; b < BB; b++) {
            if (flags[b] && flags[BB + b]) {
                s += (double)lsum[b];
                c += (double)vcnt[b];
            }
        }
        out[0] = (float)(-s / c);
    }
}

extern "C" void kernel_launch(void* const* d_in, const int* in_sizes, int n_in,
                              void* d_out, int out_size, void* d_ws, size_t ws_size,
                              hipStream_t stream) {
    const int*   z   = (const int*)  d_in[0];
    const float* x1  = (const float*)d_in[1];
    const float* x2  = (const float*)d_in[2];
    const float* tp  = (const float*)d_in[3];
    const float* bp  = (const float*)d_in[4];
    float* out = (float*)d_out;

    char* ws = (char*)d_ws;
    char*  normA = ws;                                      // 8 MiB
    char*  normB = ws + (size_t)BB * NN * 512;              // 8 MiB
    uint4* codes = (uint4*)(ws + (size_t)BB * (NN + MM) * 512);  // 8 MiB
    char*  accb  = ws + (size_t)BB * (NN + MM) * 512 + (size_t)8 * 1024 * 1024;
    float*        lsum  = (float*)accb;
    unsigned int* vcnt  = (unsigned int*)(accb + 64);
    unsigned int* flags = (unsigned int*)(accb + 128);

    hipLaunchKernelGGL(zero_acc, dim3(1), dim3(64), 0, stream, lsum, vcnt, flags);

    hipLaunchKernelGGL(norm_cast_kernel, dim3(BB * (NN + MM) / 4), dim3(256), 0, stream,
                       x1, x2, normA, normB);

    hipLaunchKernelGGL(zpack_kernel, dim3(MM / 128, NN / 128, BB), dim3(256), 0, stream,
                       z, codes);

    hipLaunchKernelGGL(fused_mfma_kernel, dim3(MM / 128, NN / 128, BB), dim3(256), 0, stream,
                       codes, normA, normB, tp, bp, lsum, vcnt, flags);

    hipLaunchKernelGGL(finalize_kernel, dim3(1), dim3(64), 0, stream,
                       lsum, vcnt, flags, out);
}

// Round 4
// 118.364 us; speedup vs baseline: 2.7589x; 1.0388x over previous
//
#include <hip/hip_runtime.h>
#include <hip/hip_bf16.h>
#include <stdint.h>

#define BB 8
#define NN 2048
#define MM 2048
#define CC 256

typedef __attribute__((ext_vector_type(8))) short short8;
typedef __attribute__((ext_vector_type(4))) float f32x4;

__device__ __forceinline__ void gl_lds16(const void* g, void* l) {
    __builtin_amdgcn_global_load_lds(
        (const __attribute__((address_space(1))) void*)g,
        (__attribute__((address_space(3))) void*)l, 16, 0, 0);
}

__device__ __forceinline__ unsigned short f2bf(float f) {
    __hip_bfloat16 h = __float2bfloat16(f);
    return *reinterpret_cast<unsigned short*>(&h);
}

// ---------------- normalize + cast + layout pre-pass ----------------
// One wave per row of C=256 floats.
// A layout (bytes):  row*512 + c*64 + kbL*16 + (lane&1)*8,  kbL = kb ^ ((row>>1)&3)
//   -> linear global_load_lds staging + swizzled ds_read (proven R3, 0 conflicts).
// B layout (bytes):  batch*1MiB + ((r>>4)*8 + c)*1024 + kbL*256 + (r&15)*16 + ...
//   -> each wave MFMA-fragment load (n,c) is a bijective permutation of a
//      contiguous 1 KiB block => fully coalesced register loads.
__global__ __launch_bounds__(256) void norm_cast_kernel(
    const float* __restrict__ x1, const float* __restrict__ x2,
    char* __restrict__ outA, char* __restrict__ outB) {
    int gwave = (blockIdx.x * blockDim.x + threadIdx.x) >> 6;
    int lane  = threadIdx.x & 63;
    bool isA = gwave < BB * NN;
    const float* src = isA ? x1 : x2;
    int row = isA ? gwave : gwave - BB * NN;
    float4 v = reinterpret_cast<const float4*>(src + (size_t)row * CC)[lane];
    float ss = v.x * v.x + v.y * v.y + v.z * v.z + v.w * v.w;
#pragma unroll
    for (int off = 32; off; off >>= 1) ss += __shfl_xor(ss, off);
    float inv = 1.0f / fmaxf(sqrtf(ss), 1e-8f);
    ushort4 h;
    h.x = f2bf(v.x * inv); h.y = f2bf(v.y * inv);
    h.z = f2bf(v.z * inv); h.w = f2bf(v.w * inv);
    int c   = lane >> 3;              // k-chunk 0..7
    int kb  = (lane >> 1) & 3;        // logical 16B k-unit
    int kbL = kb ^ ((row >> 1) & 3);  // swizzled unit
    char* p;
    if (isA) {
        p = outA + (size_t)row * 512 + c * 64 + kbL * 16 + (lane & 1) * 8;
    } else {
        int b = row >> 11, r = row & 2047;
        p = outB + (size_t)b * 1048576 + (size_t)((r >> 4) * 8 + c) * 1024
                 + kbL * 256 + (r & 15) * 16 + (lane & 1) * 8;
    }
    *reinterpret_cast<ushort4*>(p) = h;
}

// ---------------- z-pack: coalesced read -> LDS -> 2-bit codes ----------------
// Matches fused kernel's per-thread consumption order exactly.
__global__ __launch_bounds__(512) void zpack_kernel(const int* __restrict__ z,
                                                    uint2* __restrict__ codes) {
    __shared__ int zt[128 * 132];   // +4 pad per row breaks bank aliasing
    const int b   = blockIdx.z;
    const int n0  = blockIdx.y * 128;
    const int m0  = blockIdx.x * 128;
    const int tid = threadIdx.x;

#pragma unroll
    for (int i = 0; i < 8; i++) {
        int idx = i * 512 + tid;          // 0..4095 int4-units
        int row = idx >> 5;               // 128 rows
        int col = (idx & 31) * 4;         // 0..124
        int4 v = *reinterpret_cast<const int4*>(
            z + ((size_t)b * NN + n0 + row) * MM + m0 + col);
        *reinterpret_cast<int4*>(&zt[row * 132 + col]) = v;
    }
    __syncthreads();

    const int lane = tid & 63, wid = tid >> 6;
    const int wr = wid >> 2, wc = wid & 3;
    const int l15 = lane & 15, q4 = (lane >> 4) << 2;

    uint32_t w0 = 0u, w1 = 0u;
#pragma unroll
    for (int m = 0; m < 4; m++)
#pragma unroll
        for (int r = 0; r < 4; r++)
#pragma unroll
            for (int n = 0; n < 2; n++) {
                int v = zt[(wr * 64 + m * 16 + q4 + r) * 132 + wc * 32 + l15 + n * 16];
                uint32_t code = (v == 0) ? 0u : ((v > 0) ? 1u : 2u);
                int s = (m * 4 + r) * 2 + n;
                if (s < 16) w0 |= code << (s * 2);
                else        w1 |= code << ((s - 16) * 2);
            }
    size_t blk = ((size_t)b * 16 + blockIdx.y) * 16 + blockIdx.x;
    codes[blk * 512 + tid] = make_uint2(w0, w1);
}

// ---------------- accumulator zeroing ----------------
__global__ void zero_acc(float* __restrict__ lsum, unsigned int* __restrict__ vcnt,
                         unsigned int* __restrict__ flags) {
    int t = threadIdx.x;
    if (t < BB) {
        lsum[t] = 0.0f; vcnt[t] = 0u; flags[t] = 0u; flags[BB + t] = 0u;
    }
}

// ---------------- fused MFMA cos-sim + BCE reduce ----------------
// 128x128 tile, 8 waves (2x4), wave tile 64x32. A full-K in LDS (one barrier
// total), B fragments in registers (coalesced loads, compiler-managed waits).
__global__ __launch_bounds__(512, 4) void fused_mfma_kernel(
    const uint2* __restrict__ codes,
    const char* __restrict__ nA, const char* __restrict__ nB,
    const float* __restrict__ tptr, const float* __restrict__ bptr,
    float* __restrict__ lsum, unsigned int* __restrict__ vcnt,
    unsigned int* __restrict__ flags) {

    __shared__ __align__(16) char ldsA[65536];   // 8 chunks x 128 rows x 64 B
    __shared__ float        s_sum[8];
    __shared__ unsigned int s_cnt[8];
    __shared__ unsigned int s_flag[2];

    const int b   = blockIdx.z;
    const int n0  = blockIdx.y * 128;
    const int m0  = blockIdx.x * 128;
    const int tid = threadIdx.x, lane = tid & 63, wid = tid >> 6;
    const int wr = wid >> 2, wc = wid & 3, l15 = lane & 15;

    const char* gA = nA + ((size_t)b * NN + n0) * 512;

    // ---- A staging: wave `wid` stages k-chunk c=wid, row-groups g=0..7 ----
    {
        const char* src = gA + (size_t)(lane >> 2) * 512 + wid * 64 + (lane & 3) * 16;
        char* dst = ldsA + wid * 8192;
#pragma unroll
        for (int g = 0; g < 8; g++)
            gl_lds16(src + (size_t)g * 16 * 512, dst + g * 1024);
    }
    asm volatile("" ::: "memory");   // keep A-stages oldest in vm queue

    const int kbL = (lane >> 4) ^ ((l15 >> 1) & 3);

    // ---- B first half-K (c=0..3) into registers, coalesced 1KiB blocks ----
    const char* gB0 = nB + (size_t)b * 1048576 + ((size_t)(m0 >> 4)) * 8192
                    + kbL * 256 + l15 * 16;
    short8 bfA[4][2];
#pragma unroll
    for (int c = 0; c < 4; c++)
#pragma unroll
        for (int n = 0; n < 2; n++)
            bfA[c][n] = *reinterpret_cast<const short8*>(gB0 + (wc * 2 + n) * 8192 + c * 1024);

    uint2 zc = codes[(((size_t)b * 16 + blockIdx.y) * 16 + blockIdx.x) * 512 + tid];

    // A-stages are the 8 oldest vm ops; >=8 younger (bfA + codes) outstanding allowed.
    asm volatile("s_waitcnt vmcnt(8)" ::: "memory");
    __builtin_amdgcn_s_barrier();

    f32x4 acc[4][2];
#pragma unroll
    for (int m = 0; m < 4; m++)
#pragma unroll
        for (int n = 0; n < 2; n++) acc[m][n] = (f32x4){0.f, 0.f, 0.f, 0.f};

    short8 bfB[4][2];

#define STEP(c, BF)                                                                  \
    do {                                                                             \
        short8 af[4];                                                                \
        _Pragma("unroll")                                                            \
        for (int m = 0; m < 4; m++)                                                  \
            af[m] = *reinterpret_cast<const short8*>(                                \
                ldsA + (c) * 8192 + (wr * 64 + m * 16 + l15) * 64 + kbL * 16);       \
        _Pragma("unroll")                                                            \
        for (int m = 0; m < 4; m++) {                                                \
            acc[m][0] = __builtin_amdgcn_mfma_f32_16x16x32_bf16(af[m], BF[(c) & 3][0], acc[m][0], 0, 0, 0); \
            acc[m][1] = __builtin_amdgcn_mfma_f32_16x16x32_bf16(af[m], BF[(c) & 3][1], acc[m][1], 0, 0, 0); \
        }                                                                            \
    } while (0)

    STEP(0, bfA);
    STEP(1, bfA);
    // issue second half-K B loads; latency hides under c=2,3 compute
#pragma unroll
    for (int c = 0; c < 4; c++)
#pragma unroll
        for (int n = 0; n < 2; n++)
            bfB[c][n] = *reinterpret_cast<const short8*>(gB0 + (wc * 2 + n) * 8192 + (c + 4) * 1024);
    STEP(2, bfA);
    STEP(3, bfA);
    STEP(4, bfB);
    STEP(5, bfB);
    STEP(6, bfB);
    STEP(7, bfB);
#undef STEP

    // ---------------- epilogue: decode codes + log-sigmoid + reduce ----------------
    const float tv = *tptr;
    const float bs = *bptr;
    float lsu = 0.0f;
    int   lcnt = 0;
    bool  anyp = false, anyn = false;
#pragma unroll
    for (int m = 0; m < 4; m++)
#pragma unroll
        for (int r = 0; r < 4; r++)
#pragma unroll
            for (int n = 0; n < 2; n++) {
                int s = (m * 4 + r) * 2 + n;
                uint32_t word = (s < 16) ? zc.x : zc.y;
                uint32_t code = (word >> ((s & 15) * 2)) & 3u;
                if (code) {
                    float cs  = acc[m][n][r];
                    float sgn = (code == 2u) ? -1.0f : 1.0f;
                    float y   = sgn * fmaf(tv, cs, -bs);
                    float e   = __expf(-fabsf(y));
                    lsu += fminf(y, 0.0f) - __logf(1.0f + e);
                    lcnt++;
                    anyp |= (code == 1u);
                    anyn |= (code == 2u);
                }
            }

#pragma unroll
    for (int off = 32; off; off >>= 1) {
        lsu  += __shfl_down(lsu, off);
        lcnt += __shfl_down(lcnt, off);
    }
    unsigned long long mp = __ballot(anyp);
    unsigned long long mn = __ballot(anyn);

    __syncthreads();
    if (tid < 2) s_flag[tid] = 0u;
    __syncthreads();
    if (lane == 0) {
        s_sum[wid] = lsu;
        s_cnt[wid] = (unsigned int)lcnt;
        if (mp) atomicOr(&s_flag[0], 1u);
        if (mn) atomicOr(&s_flag[1], 1u);
    }
    __syncthreads();
    if (tid == 0) {
        float ts = 0.f; unsigned int tc = 0u;
#pragma unroll
        for (int w = 0; w < 8; w++) { ts += s_sum[w]; tc += s_cnt[w]; }
        atomicAdd(&lsum[b], ts);
        atomicAdd(&vcnt[b], tc);
        if (s_flag[0]) atomicOr(&flags[b], 1u);
        if (s_flag[1]) atomicOr(&flags[BB + b], 1u);
    }
}

// ---------------- finalize ----------------
__global__ void finalize_kernel(const float* __restrict__ lsum,
                                const unsigned int* __restrict__ vcnt,
                                const unsigned int* __restrict__ flags,
                                float* __restrict__ out) {
    if (threadIdx.x == 0 && blockIdx.x == 0) {
        double s = 0.0, c = 0.0;
        for (int b = 0; b < BB; b++) {
            if (flags[b] && flags[BB + b]) {
                s += (double)lsum[b];
                c += (double)vcnt[b];
            }
        }
        out[0] = (float)(-s / c);
    }
}

extern "C" void kernel_launch(void* const* d_in, const int* in_sizes, int n_in,
                              void* d_out, int out_size, void* d_ws, size_t ws_size,
                              hipStream_t stream) {
    const int*   z   = (const int*)  d_in[0];
    const float* x1  = (const float*)d_in[1];
    const float* x2  = (const float*)d_in[2];
    const float* tp  = (const float*)d_in[3];
    const float* bp  = (const float*)d_in[4];
    float* out = (float*)d_out;

    char* ws = (char*)d_ws;
    char*  normA = ws;                                           // 8 MiB
    char*  normB = ws + (size_t)BB * NN * 512;                   // 8 MiB
    uint2* codes = (uint2*)(ws + (size_t)BB * (NN + MM) * 512);  // 8 MiB
    char*  accb  = ws + (size_t)BB * (NN + MM) * 512 + (size_t)8 * 1024 * 1024;
    float*        lsum  = (float*)accb;
    unsigned int* vcnt  = (unsigned int*)(accb + 64);
    unsigned int* flags = (unsigned int*)(accb + 128);

    hipLaunchKernelGGL(zero_acc, dim3(1), dim3(64), 0, stream, lsum, vcnt, flags);

    hipLaunchKernelGGL(norm_cast_kernel, dim3(BB * (NN + MM) / 4), dim3(256), 0, stream,
                       x1, x2, normA, normB);

    hipLaunchKernelGGL(zpack_kernel, dim3(MM / 128, NN / 128, BB), dim3(512), 0, stream,
                       z, codes);

    hipLaunchKernelGGL(fused_mfma_kernel, dim3(MM / 128, NN / 128, BB), dim3(512), 0, stream,
                       codes, normA, normB, tp, bp, lsum, vcnt, flags);

    hipLaunchKernelGGL(finalize_kernel, dim3(1), dim3(64), 0, stream,
                       lsum, vcnt, flags, out);
}

// Round 5
// 67.768 us; speedup vs baseline: 4.8187x; 1.7466x over previous
//
#include <hip/hip_runtime.h>
#include <hip/hip_bf16.h>
#include <stdint.h>

#define BB 8
#define NN 2048
#define MM 2048
#define CC 256

typedef __attribute__((ext_vector_type(8))) short short8;
typedef __attribute__((ext_vector_type(4))) float f32x4;

__device__ __forceinline__ void gl_lds16(const void* g, void* l) {
    __builtin_amdgcn_global_load_lds(
        (const __attribute__((address_space(1))) void*)g,
        (__attribute__((address_space(3))) void*)l, 16, 0, 0);
}

__device__ __forceinline__ unsigned short f2bf(float f) {
    __hip_bfloat16 h = __float2bfloat16(f);
    return *reinterpret_cast<unsigned short*>(&h);
}

// ---------------- normalize + cast + layout pre-pass ----------------
// One wave per row of C=256 floats.
// A layout (bytes):  row*512 + c*64 + kbL*16 + (lane&1)*8,  kbL = kb ^ ((row>>1)&3)
//   -> linear global_load_lds staging + swizzled ds_read (0 conflicts, proven).
// B layout (bytes):  batch*1MiB + ((r>>4)*8 + c)*1024 + kbL*256 + (r&15)*16 + ...
//   -> each wave MFMA B-fragment load is a bijective permutation of a
//      contiguous 1 KiB block => fully coalesced register loads.
__global__ __launch_bounds__(256) void norm_cast_kernel(
    const float* __restrict__ x1, const float* __restrict__ x2,
    char* __restrict__ outA, char* __restrict__ outB) {
    int gwave = (blockIdx.x * blockDim.x + threadIdx.x) >> 6;
    int lane  = threadIdx.x & 63;
    bool isA = gwave < BB * NN;
    const float* src = isA ? x1 : x2;
    int row = isA ? gwave : gwave - BB * NN;
    float4 v = reinterpret_cast<const float4*>(src + (size_t)row * CC)[lane];
    float ss = v.x * v.x + v.y * v.y + v.z * v.z + v.w * v.w;
#pragma unroll
    for (int off = 32; off; off >>= 1) ss += __shfl_xor(ss, off);
    float inv = 1.0f / fmaxf(sqrtf(ss), 1e-8f);
    ushort4 h;
    h.x = f2bf(v.x * inv); h.y = f2bf(v.y * inv);
    h.z = f2bf(v.z * inv); h.w = f2bf(v.w * inv);
    int c   = lane >> 3;              // k-chunk 0..7
    int kb  = (lane >> 1) & 3;        // logical 16B k-unit
    int kbL = kb ^ ((row >> 1) & 3);  // swizzled unit
    char* p;
    if (isA) {
        p = outA + (size_t)row * 512 + c * 64 + kbL * 16 + (lane & 1) * 8;
    } else {
        int b = row >> 11, r = row & 2047;
        p = outB + (size_t)b * 1048576 + (size_t)((r >> 4) * 8 + c) * 1024
                 + kbL * 256 + (r & 15) * 16 + (lane & 1) * 8;
    }
    *reinterpret_cast<ushort4*>(p) = h;
}

// ---------------- accumulator zeroing ----------------
__global__ void zero_acc(float* __restrict__ lsum, unsigned int* __restrict__ vcnt,
                         unsigned int* __restrict__ flags) {
    int t = threadIdx.x;
    if (t < BB) {
        lsum[t] = 0.0f; vcnt[t] = 0u; flags[t] = 0u; flags[BB + t] = 0u;
    }
}

// ---------------- fused MFMA cos-sim + BCE reduce (multi-tile) ----------------
// 512 blocks (all co-resident, 2/CU), XCD-swizzled: b = blockIdx&7 so each XCD
// owns one batch (A+B panels L2-resident). Each block: one 128-row A-panel
// full-K in LDS (staged once), then 4 m-tiles of 128 cols; B fragments and z
// labels stream into registers, epilogue fused per tile.
__global__ __launch_bounds__(512, 4) void fused_mfma_kernel(
    const int*  __restrict__ z,
    const char* __restrict__ nA, const char* __restrict__ nB,
    const float* __restrict__ tptr, const float* __restrict__ bptr,
    float* __restrict__ lsum, unsigned int* __restrict__ vcnt,
    unsigned int* __restrict__ flags) {

    __shared__ __align__(16) char ldsA[65536];   // 8 k-chunks x 128 rows x 64 B
    __shared__ float        s_sum[8];
    __shared__ unsigned int s_cnt[8];
    __shared__ unsigned int s_flag[2];

    const int flat = blockIdx.x;
    const int b    = flat & 7;           // XCD id == batch
    const int rest = flat >> 3;
    const int n0   = (rest & 15) * 128;
    const int mq   = rest >> 4;          // 0..3 (m-quarter: 4 tiles of 128)
    const int tid  = threadIdx.x, lane = tid & 63, wid = tid >> 6;
    const int wr = wid >> 2, wc = wid & 3, l15 = lane & 15;
    const int kbL = (lane >> 4) ^ ((l15 >> 1) & 3);

    // ---- A staging: wave `wid` stages k-chunk c=wid, row-groups g=0..7 ----
    {
        const char* src = nA + ((size_t)b * NN + n0) * 512
                        + (size_t)(lane >> 2) * 512 + wid * 64 + (lane & 3) * 16;
        char* dst = ldsA + wid * 8192;
#pragma unroll
        for (int g = 0; g < 8; g++)
            gl_lds16(src + (size_t)g * 8192, dst + g * 1024);
    }

    const char* gB0 = nB + (size_t)b * 1048576 + (size_t)mq * 262144
                    + kbL * 256 + l15 * 16;
    const int* zb = z + ((size_t)b * NN + n0 + wr * 64 + ((lane >> 4) << 2)) * MM
                      + mq * 512 + wc * 32 + l15;

    const float tv = *tptr;
    const float bs = *bptr;

    __syncthreads();   // A-slab resident (drains vmcnt/lgkmcnt for all waves)

    float lsu = 0.0f;
    int   lcnt = 0;
    bool  anyp = false, anyn = false;

#pragma unroll
    for (int mt = 0; mt < 4; mt++) {
        const char* gBt = gB0 + mt * 65536;

        // issue B fragments (16 x dwordx4, coalesced 1 KiB blocks)
        short8 bfr[8][2];
#pragma unroll
        for (int c = 0; c < 8; c++)
#pragma unroll
            for (int n = 0; n < 2; n++)
                bfr[c][n] = *reinterpret_cast<const short8*>(
                    gBt + (wc * 2 + n) * 8192 + c * 1024);

        // issue z labels (32 dwords, 64B-segment coalesced); consumed ~900cy later
        int zr[32];
#pragma unroll
        for (int m = 0; m < 4; m++)
#pragma unroll
            for (int r = 0; r < 4; r++)
#pragma unroll
                for (int n = 0; n < 2; n++)
                    zr[(m * 4 + r) * 2 + n] = zb[mt * 128 + (m * 16 + r) * MM + n * 16];

        // MFMA over full K
        f32x4 acc[4][2] = {};
#pragma unroll
        for (int c = 0; c < 8; c++) {
            short8 af[4];
#pragma unroll
            for (int m = 0; m < 4; m++)
                af[m] = *reinterpret_cast<const short8*>(
                    ldsA + c * 8192 + (wr * 64 + m * 16 + l15) * 64 + kbL * 16);
#pragma unroll
            for (int m = 0; m < 4; m++) {
                acc[m][0] = __builtin_amdgcn_mfma_f32_16x16x32_bf16(af[m], bfr[c][0], acc[m][0], 0, 0, 0);
                acc[m][1] = __builtin_amdgcn_mfma_f32_16x16x32_bf16(af[m], bfr[c][1], acc[m][1], 0, 0, 0);
            }
        }

        // fused epilogue for this tile
#pragma unroll
        for (int m = 0; m < 4; m++)
#pragma unroll
            for (int r = 0; r < 4; r++)
#pragma unroll
                for (int n = 0; n < 2; n++) {
                    int zij = zr[(m * 4 + r) * 2 + n];
                    if (zij != 0) {
                        float cs  = acc[m][n][r];
                        float sgn = (zij > 0) ? 1.0f : -1.0f;
                        float y   = sgn * fmaf(tv, cs, -bs);
                        float e   = __expf(-fabsf(y));
                        lsu += fminf(y, 0.0f) - __logf(1.0f + e);
                        lcnt++;
                        anyp |= (zij > 0);
                        anyn |= (zij < 0);
                    }
                }
    }

    // ---------------- block reduction ----------------
#pragma unroll
    for (int off = 32; off; off >>= 1) {
        lsu  += __shfl_down(lsu, off);
        lcnt += __shfl_down(lcnt, off);
    }
    unsigned long long mp = __ballot(anyp);
    unsigned long long mn = __ballot(anyn);

    __syncthreads();
    if (tid < 2) s_flag[tid] = 0u;
    __syncthreads();
    if (lane == 0) {
        s_sum[wid] = lsu;
        s_cnt[wid] = (unsigned int)lcnt;
        if (mp) atomicOr(&s_flag[0], 1u);
        if (mn) atomicOr(&s_flag[1], 1u);
    }
    __syncthreads();
    if (tid == 0) {
        float ts = 0.f; unsigned int tc = 0u;
#pragma unroll
        for (int w = 0; w < 8; w++) { ts += s_sum[w]; tc += s_cnt[w]; }
        atomicAdd(&lsum[b], ts);
        atomicAdd(&vcnt[b], tc);
        if (s_flag[0]) atomicOr(&flags[b], 1u);
        if (s_flag[1]) atomicOr(&flags[BB + b], 1u);
    }
}

// ---------------- finalize ----------------
__global__ void finalize_kernel(const float* __restrict__ lsum,
                                const unsigned int* __restrict__ vcnt,
                                const unsigned int* __restrict__ flags,
                                float* __restrict__ out) {
    if (threadIdx.x == 0 && blockIdx.x == 0) {
        double s = 0.0, c = 0.0;
        for (int b = 0; b < BB; b++) {
            if (flags[b] && flags[BB + b]) {
                s += (double)lsum[b];
                c += (double)vcnt[b];
            }
        }
        out[0] = (float)(-s / c);
    }
}

extern "C" void kernel_launch(void* const* d_in, const int* in_sizes, int n_in,
                              void* d_out, int out_size, void* d_ws, size_t ws_size,
                              hipStream_t stream) {
    const int*   z   = (const int*)  d_in[0];
    const float* x1  = (const float*)d_in[1];
    const float* x2  = (const float*)d_in[2];
    const float* tp  = (const float*)d_in[3];
    const float* bp  = (const float*)d_in[4];
    float* out = (float*)d_out;

    char* ws = (char*)d_ws;
    char*  normA = ws;                                  // 8 MiB
    char*  normB = ws + (size_t)BB * NN * 512;          // 8 MiB
    char*  accb  = ws + (size_t)BB * (NN + MM) * 512;
    float*        lsum  = (float*)accb;
    unsigned int* vcnt  = (unsigned int*)(accb + 64);
    unsigned int* flags = (unsigned int*)(accb + 128);

    hipLaunchKernelGGL(zero_acc, dim3(1), dim3(64), 0, stream, lsum, vcnt, flags);

    hipLaunchKernelGGL(norm_cast_kernel, dim3(BB * (NN + MM) / 4), dim3(256), 0, stream,
                       x1, x2, normA, normB);

    hipLaunchKernelGGL(fused_mfma_kernel, dim3(512), dim3(512), 0, stream,
                       z, normA, normB, tp, bp, lsum, vcnt, flags);

    hipLaunchKernelGGL(finalize_kernel, dim3(1), dim3(64), 0, stream,
                       lsum, vcnt, flags, out);
}